// Round 10
// baseline (148.492 us; speedup 1.0000x reference)
//
#include <hip/hip_runtime.h>
#include <math.h>

// Shapes fixed by the reference's setup_inputs()
#define B_ 4
#define N_ 8192
#define M_ 8192
#define O_ 32
#define E_ 128
#define F_ 128
#define K_ 8

#define LOG_HALF_F (-0.6931471805599453f)
#define GUARD_F 1e-7f

typedef float f4v __attribute__((ext_vector_type(4)));

// One 128-thread block (2 waves) per (b, m) pair.
// __launch_bounds__(128, 6): 6 waves/EU -> 12 blocks/CU, VGPR cap ~84.
// DO NOT raise to (128,8): the 64-VGPR cap spills the pinned xv[32] array
// to scratch (+~1 GB of HBM traffic, 3x slowdown — measured round 6).
__global__ __launch_bounds__(128, 6) void n3agg_kernel(
    const float* __restrict__ x,        // (B,N,F)
    const float* __restrict__ xe,       // (B,N,E)
    const float* __restrict__ ye,       // (B,M,E)
    const float* __restrict__ log_temp, // (1,)
    const int*   __restrict__ I,        // (B,M,O)
    float*       __restrict__ out)      // (B,M,F,K)
{
    __shared__ float s_logits[O_];
    __shared__ float s_W[O_ * K_];     // [o][k]: 2x ds_read_b128 broadcast per o
    __shared__ float s_out[F_ * K_];   // 4 KiB staging for full-line output stores

    const int t  = threadIdx.x;
    // Batch->XCD-pair swizzle (round 9: ~neutral on FETCH, slight dur win; kept).
    const int bid = blockIdx.x;
    const int p   = bid & 7;
    const int bm  = ((p >> 1) << 13) | ((p & 1) << 12) | (bid >> 3);  // b*M + m
    const int b   = bm >> 13;            // / M_

    const float inv_temp = 1.0f / expf(log_temp[0]);

    // ---- distance phase: 32 groups x 4 lanes, contiguous per-group access ----
    // lane l of group g reads float4 at element offset (j*4+l)*4: the 4 lanes
    // cover 64 contiguous bytes per j -> dense cache lines, each touched once.
    {
        const int g = t >> 2;   // candidate o (0..31 across the 2 waves)
        const int l = t & 3;    // lane within group
        const int idxg = I[(size_t)bm * O_ + g];
        const float4* yrow = (const float4*)(ye + (size_t)bm * E_);
        const float4* xrow = (const float4*)(xe + ((size_t)b * N_ + idxg) * E_);
        float acc = 0.f;
        #pragma unroll
        for (int j = 0; j < 8; ++j) {
            float4 yv = yrow[j * 4 + l];
            float4 xv = xrow[j * 4 + l];
            float d0 = xv.x - yv.x, d1 = xv.y - yv.y;
            float d2 = xv.z - yv.z, d3 = xv.w - yv.w;
            acc += d0 * d0 + d1 * d1 + d2 * d2 + d3 * d3;
        }
        acc += __shfl_xor(acc, 1);
        acc += __shfl_xor(acc, 2);
        if (l == 0) s_logits[g] = -acc * inv_temp;   // D / temperature
    }

    // ---- prefetch ALL 32 gathered x values (thread t owns f=t). ----
    // Irow is block-uniform -> SGPR loads. asm pins keep the loads HERE so
    // the gather latency hides under the softmax.
    const int* Irow = I + (size_t)bm * O_;
    const float* xb = x + (size_t)b * (N_ * F_) + t;
    float xv[O_];
    #pragma unroll
    for (int o = 0; o < O_; ++o) {
        xv[o] = xb[(size_t)(Irow[o] * F_)];
    }
    #pragma unroll
    for (int o = 0; o < O_; ++o) {
        asm volatile("" : "+v"(xv[o]));   // keep live across softmax, no code
    }

    __syncthreads();   // s_logits ready

    // ---- K-step relaxed top-k softmax: wave 0, lanes 0..31 (one lane per o) ----
    if (t < O_) {
        float logit = s_logits[t];
        float wloc[K_];
        #pragma unroll
        for (int k = 0; k < K_; ++k) {
            float mx = logit;
            #pragma unroll
            for (int d = 16; d >= 1; d >>= 1) mx = fmaxf(mx, __shfl_xor(mx, d, 32));
            float sh = logit - mx;
            float ev = __expf(sh);
            float sm = ev;
            #pragma unroll
            for (int d = 16; d >= 1; d >>= 1) sm += __shfl_xor(sm, d, 32);
            // sh=0 at the max lane -> sm >= 1 exactly -> w <= 0 -> Taylor p <= 0
            // -> arg = GUARD - p > 0 always (no NaN branch with fast log).
            float w = sh - __logf(sm);
            float sample = __expf(w);
            wloc[k] = sample;
            // log1mexp(w), reference branch + guard semantics:
            //  w <  log(0.5): log1p(-exp(w)) == log(1 - sample), no cancellation
            //  w >= log(0.5): log(-expm1(w) + 1e-7), expm1 via deg-7 Taylor
            float p7 = w * (1.0f + w * (0.5f + w * (0.16666667f + w * (4.1666667e-2f
                     + w * (8.3333333e-3f + w * (1.3888889e-3f + w * 1.9841270e-4f))))));
            float arg = (w < LOG_HALF_F) ? (1.0f - sample) : (GUARD_F - p7);
            logit += __logf(arg);
        }
        ((float4*)&s_W[t * K_])[0] = make_float4(wloc[0], wloc[1], wloc[2], wloc[3]);
        ((float4*)&s_W[t * K_])[1] = make_float4(wloc[4], wloc[5], wloc[6], wloc[7]);
    }
    __syncthreads();   // s_W ready

    // ---- aggregation: thread t owns f = t; W via LDS broadcast, x from regs ----
    {
        float acc[K_];
        #pragma unroll
        for (int k = 0; k < K_; ++k) acc[k] = 0.f;
        #pragma unroll
        for (int o = 0; o < O_; ++o) {
            const float4 w0 = ((const float4*)&s_W[o * K_])[0];
            const float4 w1 = ((const float4*)&s_W[o * K_])[1];
            const float xvo = xv[o];
            acc[0] = fmaf(xvo, w0.x, acc[0]);
            acc[1] = fmaf(xvo, w0.y, acc[1]);
            acc[2] = fmaf(xvo, w0.z, acc[2]);
            acc[3] = fmaf(xvo, w0.w, acc[3]);
            acc[4] = fmaf(xvo, w1.x, acc[4]);
            acc[5] = fmaf(xvo, w1.y, acc[5]);
            acc[6] = fmaf(xvo, w1.z, acc[6]);
            acc[7] = fmaf(xvo, w1.w, acc[7]);
        }
        // Stage through LDS so each global store instruction covers FULL 64B
        // lines (wave = 1 KiB contiguous).
        ((float4*)&s_out[t * K_])[0] = make_float4(acc[0], acc[1], acc[2], acc[3]);
        ((float4*)&s_out[t * K_])[1] = make_float4(acc[4], acc[5], acc[6], acc[7]);
    }
    __syncthreads();   // s_out ready (cross-lane exchange)

    {
        // Block output chunk: out + bm*1024 floats (4 KiB contiguous).
        // ROUND 10 EXPERIMENT: plain cached stores on the full-line layout.
        // Store-mode matrix so far: strided+plain = 3.0x WRITE + write-allocate
        // FETCH (r7); strided+NT = 1.83x (r5); full-line+NT = 1.75x (r8/r9 —
        // NT write-through never merges to full lines at HBM). Full-line+plain
        // should dirty complete 64B lines in L2 -> no write-allocate read, one
        // writeback each -> WRITE = 131 MB exact. Risk: output stream evicts
        // gather lines from L2 (watch FETCH).
        const f4v* src = (const f4v*)s_out;
        f4v v0 = src[t];
        f4v v1 = src[128 + t];
        f4v* dst = (f4v*)(out + (size_t)bm * (F_ * K_));
        dst[t]       = v0;
        dst[128 + t] = v1;
    }
}

extern "C" void kernel_launch(void* const* d_in, const int* in_sizes, int n_in,
                              void* d_out, int out_size, void* d_ws, size_t ws_size,
                              hipStream_t stream) {
    const float* x        = (const float*)d_in[0];
    const float* xe       = (const float*)d_in[1];
    const float* ye       = (const float*)d_in[2];
    const float* log_temp = (const float*)d_in[3];
    const int*   I        = (const int*)d_in[4];
    float* out = (float*)d_out;

    dim3 grid(B_ * M_);
    dim3 block(128);
    hipLaunchKernelGGL(n3agg_kernel, grid, block, 0, stream,
                       x, xe, ye, log_temp, I, out);
}

// Round 11
// 106.633 us; speedup vs baseline: 1.3926x; 1.3926x over previous
//
#include <hip/hip_runtime.h>
#include <math.h>

// Shapes fixed by the reference's setup_inputs()
#define B_ 4
#define N_ 8192
#define M_ 8192
#define O_ 32
#define E_ 128
#define F_ 128
#define K_ 8

#define LOG_HALF_F (-0.6931471805599453f)
#define GUARD_F 1e-7f

typedef float f4v __attribute__((ext_vector_type(4)));

// One 128-thread block (2 waves) per (b, m) pair.
// __launch_bounds__(128, 8): 8 waves/EU -> 16 blocks/CU (occupancy tracks this
// arg: r6 measured 87.7% at 8 vs 63% at 6). The 64-VGPR cap is now SAFE
// because only 16 x-values are pinned across the softmax (r6 spilled with 32
// pinned -> +1GB scratch traffic; peak live set here ~50 VGPR).
__global__ __launch_bounds__(128, 8) void n3agg_kernel(
    const float* __restrict__ x,        // (B,N,F)
    const float* __restrict__ xe,       // (B,N,E)
    const float* __restrict__ ye,       // (B,M,E)
    const float* __restrict__ log_temp, // (1,)
    const int*   __restrict__ I,        // (B,M,O)
    float*       __restrict__ out)      // (B,M,F,K)
{
    __shared__ float s_logits[O_];
    __shared__ float s_W[O_ * K_];     // [o][k]: 2x ds_read_b128 broadcast per o
    __shared__ float s_out[F_ * K_];   // 4 KiB staging for full-line output stores

    const int t  = threadIdx.x;
    // Batch->XCD-pair swizzle (round 9: small dur win; kept).
    const int bid = blockIdx.x;
    const int p   = bid & 7;
    const int bm  = ((p >> 1) << 13) | ((p & 1) << 12) | (bid >> 3);  // b*M + m
    const int b   = bm >> 13;            // / M_

    const float inv_temp = 1.0f / expf(log_temp[0]);

    // ---- distance phase: 32 groups x 4 lanes, contiguous per-group access ----
    // lane l of group g reads float4 at element offset (j*4+l)*4: the 4 lanes
    // cover 64 contiguous bytes per j -> dense cache lines, each touched once.
    {
        const int g = t >> 2;   // candidate o (0..31 across the 2 waves)
        const int l = t & 3;    // lane within group
        const int idxg = I[(size_t)bm * O_ + g];
        const float4* yrow = (const float4*)(ye + (size_t)bm * E_);
        const float4* xrow = (const float4*)(xe + ((size_t)b * N_ + idxg) * E_);
        float acc = 0.f;
        #pragma unroll
        for (int j = 0; j < 8; ++j) {
            float4 yv = yrow[j * 4 + l];
            float4 xv = xrow[j * 4 + l];
            float d0 = xv.x - yv.x, d1 = xv.y - yv.y;
            float d2 = xv.z - yv.z, d3 = xv.w - yv.w;
            acc += d0 * d0 + d1 * d1 + d2 * d2 + d3 * d3;
        }
        acc += __shfl_xor(acc, 1);
        acc += __shfl_xor(acc, 2);
        if (l == 0) s_logits[g] = -acc * inv_temp;   // D / temperature
    }

    // ---- prefetch HALF the gathered x values (o = 0..15) before the softmax.
    // 16 pins fit the 64-VGPR cap; the other 16 loads are issued after the
    // s_W barrier, where their latency hides under the first 16 o's FMAs.
    const int* Irow = I + (size_t)bm * O_;
    const float* xb = x + (size_t)b * (N_ * F_) + t;
    float xv[O_ / 2];
    #pragma unroll
    for (int o = 0; o < O_ / 2; ++o) {
        xv[o] = xb[(size_t)(Irow[o] * F_)];
    }
    #pragma unroll
    for (int o = 0; o < O_ / 2; ++o) {
        asm volatile("" : "+v"(xv[o]));   // keep live across softmax, no code
    }

    __syncthreads();   // s_logits ready

    // ---- K-step relaxed top-k softmax: wave 0, lanes 0..31 (one lane per o) ----
    if (t < O_) {
        float logit = s_logits[t];
        float wloc[K_];
        #pragma unroll
        for (int k = 0; k < K_; ++k) {
            float mx = logit;
            #pragma unroll
            for (int d = 16; d >= 1; d >>= 1) mx = fmaxf(mx, __shfl_xor(mx, d, 32));
            float sh = logit - mx;
            float ev = __expf(sh);
            float sm = ev;
            #pragma unroll
            for (int d = 16; d >= 1; d >>= 1) sm += __shfl_xor(sm, d, 32);
            // sh=0 at the max lane -> sm >= 1 exactly -> w <= 0 -> Taylor p <= 0
            // -> arg = GUARD - p > 0 always (no NaN branch with fast log).
            float w = sh - __logf(sm);
            float sample = __expf(w);
            wloc[k] = sample;
            // log1mexp(w), reference branch + guard semantics:
            //  w <  log(0.5): log1p(-exp(w)) == log(1 - sample), no cancellation
            //  w >= log(0.5): log(-expm1(w) + 1e-7), expm1 via deg-7 Taylor
            float p7 = w * (1.0f + w * (0.5f + w * (0.16666667f + w * (4.1666667e-2f
                     + w * (8.3333333e-3f + w * (1.3888889e-3f + w * 1.9841270e-4f))))));
            float arg = (w < LOG_HALF_F) ? (1.0f - sample) : (GUARD_F - p7);
            logit += __logf(arg);
        }
        ((float4*)&s_W[t * K_])[0] = make_float4(wloc[0], wloc[1], wloc[2], wloc[3]);
        ((float4*)&s_W[t * K_])[1] = make_float4(wloc[4], wloc[5], wloc[6], wloc[7]);
    }
    __syncthreads();   // s_W ready

    // ---- aggregation: thread t owns f = t; W via LDS broadcast ----
    {
        // Issue the second-half x gathers NOW; they complete while the
        // first-half FMAs + LDS broadcasts execute (T14 issue-early pattern).
        float xw[O_ / 2];
        #pragma unroll
        for (int o = 0; o < O_ / 2; ++o) {
            xw[o] = xb[(size_t)(Irow[o + O_ / 2] * F_)];
        }

        float acc[K_];
        #pragma unroll
        for (int k = 0; k < K_; ++k) acc[k] = 0.f;

        #pragma unroll
        for (int o = 0; o < O_ / 2; ++o) {
            const float4 w0 = ((const float4*)&s_W[o * K_])[0];
            const float4 w1 = ((const float4*)&s_W[o * K_])[1];
            const float xvo = xv[o];
            acc[0] = fmaf(xvo, w0.x, acc[0]);
            acc[1] = fmaf(xvo, w0.y, acc[1]);
            acc[2] = fmaf(xvo, w0.z, acc[2]);
            acc[3] = fmaf(xvo, w0.w, acc[3]);
            acc[4] = fmaf(xvo, w1.x, acc[4]);
            acc[5] = fmaf(xvo, w1.y, acc[5]);
            acc[6] = fmaf(xvo, w1.z, acc[6]);
            acc[7] = fmaf(xvo, w1.w, acc[7]);
        }
        #pragma unroll
        for (int o = 0; o < O_ / 2; ++o) {
            const int oo = o + O_ / 2;
            const float4 w0 = ((const float4*)&s_W[oo * K_])[0];
            const float4 w1 = ((const float4*)&s_W[oo * K_])[1];
            const float xvo = xw[o];
            acc[0] = fmaf(xvo, w0.x, acc[0]);
            acc[1] = fmaf(xvo, w0.y, acc[1]);
            acc[2] = fmaf(xvo, w0.z, acc[2]);
            acc[3] = fmaf(xvo, w0.w, acc[3]);
            acc[4] = fmaf(xvo, w1.x, acc[4]);
            acc[5] = fmaf(xvo, w1.y, acc[5]);
            acc[6] = fmaf(xvo, w1.z, acc[6]);
            acc[7] = fmaf(xvo, w1.w, acc[7]);
        }

        // Stage through LDS so each global store instruction covers full 64B
        // lines (wave = 1 KiB contiguous).
        ((float4*)&s_out[t * K_])[0] = make_float4(acc[0], acc[1], acc[2], acc[3]);
        ((float4*)&s_out[t * K_])[1] = make_float4(acc[4], acc[5], acc[6], acc[7]);
    }
    __syncthreads();   // s_out ready (cross-lane exchange)

    {
        // Block output chunk: out + bm*1024 floats (4 KiB contiguous).
        // Full-line NT stores: best measured write mode (r8-r10 matrix:
        // strided+plain 3.0x, strided+NT 1.83x, full-line+NT 1.75x,
        // full-line+plain 1.75x but +17MB FETCH from L2 pollution).
        const f4v* src = (const f4v*)s_out;
        f4v v0 = src[t];
        f4v v1 = src[128 + t];
        f4v* dst = (f4v*)(out + (size_t)bm * (F_ * K_));
        __builtin_nontemporal_store(v0, dst + t);
        __builtin_nontemporal_store(v1, dst + 128 + t);
    }
}

extern "C" void kernel_launch(void* const* d_in, const int* in_sizes, int n_in,
                              void* d_out, int out_size, void* d_ws, size_t ws_size,
                              hipStream_t stream) {
    const float* x        = (const float*)d_in[0];
    const float* xe       = (const float*)d_in[1];
    const float* ye       = (const float*)d_in[2];
    const float* log_temp = (const float*)d_in[3];
    const int*   I        = (const int*)d_in[4];
    float* out = (float*)d_out;

    dim3 grid(B_ * M_);
    dim3 block(128);
    hipLaunchKernelGGL(n3agg_kernel, grid, block, 0, stream,
                       x, xe, ye, log_temp, I, out);
}